// Round 1
// baseline (24917.679 us; speedup 1.0000x reference)
//
#include <hip/hip_runtime.h>
#include <hip/hip_bf16.h>

#define S_SPK 2
#define BATCH 16
#define TMAX 300
#define CLASSES 3000
#define NUM_STATES 400
#define NUM_ARCS 1200
#define DEN_STATES 3000
#define DEN_ARCS 60000
#define NEGF -1e30f

// ---------------------------------------------------------------------------
// Pack (src, dst, label, weight) into int4 for one dwordx4 load per arc.
// ---------------------------------------------------------------------------
__global__ void pack_arcs(const int* __restrict__ src, const int* __restrict__ dst,
                          const int* __restrict__ lab, const float* __restrict__ w,
                          int4* __restrict__ out, int n) {
    int i = blockIdx.x * blockDim.x + threadIdx.x;
    if (i < n) out[i] = make_int4(src[i], dst[i], lab[i], __float_as_int(w[i]));
}

// ---------------------------------------------------------------------------
// Generic FSA forward (log-domain) with per-step renormalization.
// Block = 1024 threads. alpha/sums/llh live in LDS.
// ---------------------------------------------------------------------------
__device__ __forceinline__ void fsa_forward(
    int nStates, int nArcs, const int4* __restrict__ arcs,
    const float* __restrict__ start, const float* __restrict__ fin,
    const float* __restrict__ est_base, int L, float* __restrict__ out,
    float* alpha, float* sums, float* llh, float* red)
{
    const int tid = threadIdx.x;
    const int lane = tid & 63;
    const int wid = tid >> 6;

    for (int j = tid; j < nStates; j += 1024) alpha[j] = start[j];
    float off = 0.f;
    __syncthreads();

    for (int t = 0; t < L; ++t) {
        const float* row = est_base + (size_t)t * CLASSES;
        // stage llh row + clear sums
        for (int j = tid; j < CLASSES; j += 1024) llh[j] = row[j];
        for (int j = tid; j < nStates; j += 1024) sums[j] = 0.f;
        __syncthreads();

        // arc scatter: sums[dst] += exp(alpha[src] + w + llh[lab])
        for (int i = tid; i < nArcs; i += 1024) {
            int4 a = arcs[i];
            float sc = alpha[a.x] + __int_as_float(a.w) + llh[a.z];
            // alpha renormalized so max==0; w<=0; llh<=0  ->  sc<=0, exp<=1
            atomicAdd(&sums[a.y], __expf(sc));
        }
        __syncthreads();

        // new alpha = log(sums) (or NEG), find block max for renormalization
        float lmax = -3.0e38f;
        for (int j = tid; j < nStates; j += 1024) {
            float v = sums[j];
            float na = (v > 0.f) ? __logf(v) : NEGF;
            alpha[j] = na;
            lmax = fmaxf(lmax, na);
        }
        #pragma unroll
        for (int o = 32; o > 0; o >>= 1) lmax = fmaxf(lmax, __shfl_down(lmax, o, 64));
        if (lane == 0) red[wid] = lmax;
        __syncthreads();
        if (tid < 64) {
            float v = (tid < 16) ? red[tid] : -3.0e38f;
            #pragma unroll
            for (int o = 8; o > 0; o >>= 1) v = fmaxf(v, __shfl_down(v, o, 64));
            if (tid == 0) red[0] = v;
        }
        __syncthreads();
        float m = red[0];
        off += m;
        for (int j = tid; j < nStates; j += 1024) alpha[j] -= m;
        __syncthreads();
    }

    // logZ = off + log(sum exp(alpha + final))
    float lsum = 0.f;
    for (int j = tid; j < nStates; j += 1024) lsum += __expf(alpha[j] + fin[j]);
    #pragma unroll
    for (int o = 32; o > 0; o >>= 1) lsum += __shfl_down(lsum, o, 64);
    if (lane == 0) red[wid] = lsum;
    __syncthreads();
    if (tid == 0) {
        float sTot = 0.f;
        #pragma unroll
        for (int k = 0; k < 16; ++k) sTot += red[k];
        *out = off + __logf(sTot);
    }
}

// ---------------------------------------------------------------------------
// Fused forward kernel: blocks 0..31 = den (s,b); blocks 32..95 = num (s,p,b).
// ---------------------------------------------------------------------------
__global__ __launch_bounds__(1024) void forward_kernel(
    const float* __restrict__ est, const int* __restrict__ seqlen,
    const int4* __restrict__ den_arcs, const float* __restrict__ den_start,
    const float* __restrict__ den_final,
    const int4* __restrict__ num_arcs, const float* __restrict__ num_start,
    const float* __restrict__ num_final,
    float* __restrict__ den_z, float* __restrict__ num_z)
{
    __shared__ float alpha[DEN_STATES];
    __shared__ float sums[DEN_STATES];
    __shared__ float llh[CLASSES];
    __shared__ float red[16];

    int blk = blockIdx.x;
    if (blk < S_SPK * BATCH) {
        // denominator: blk = s*16 + b
        int b = blk & 15;
        int L = seqlen[b];
        fsa_forward(DEN_STATES, DEN_ARCS, den_arcs, den_start, den_final,
                    est + (size_t)blk * TMAX * CLASSES, L, &den_z[blk],
                    alpha, sums, llh, red);
    } else {
        // numerator: q = (s*2+p)*16 + b
        int q = blk - S_SPK * BATCH;
        int b = q & 15;
        int sp = q >> 4;
        int s = sp >> 1, p = sp & 1;
        int L = seqlen[b];
        int g = p * BATCH + b;  // graph index into (p, b, ...)
        fsa_forward(NUM_STATES, NUM_ARCS, num_arcs + (size_t)g * NUM_ARCS,
                    num_start + (size_t)g * NUM_STATES,
                    num_final + (size_t)g * NUM_STATES,
                    est + (size_t)(s * BATCH + b) * TMAX * CLASSES, L, &num_z[q],
                    alpha, sums, llh, red);
    }
}

// ---------------------------------------------------------------------------
// Epilogue: best permutation per utterance, loss sum.
// perms = [(0,1), (1,0)]; argmax ties -> first (perm0).
// ---------------------------------------------------------------------------
__global__ void loss_kernel(const float* __restrict__ den_z,
                            const float* __restrict__ num_z,
                            float* __restrict__ out)
{
    int tid = threadIdx.x;  // single wave of 64
    float l = 0.f;
    if (tid < BATCH) {
        int b = tid;
        float z00 = num_z[(0 * 2 + 0) * BATCH + b];  // s=0, p=0
        float z01 = num_z[(0 * 2 + 1) * BATCH + b];  // s=0, p=1
        float z10 = num_z[(1 * 2 + 0) * BATCH + b];  // s=1, p=0
        float z11 = num_z[(1 * 2 + 1) * BATCH + b];  // s=1, p=1
        float perm0 = z00 + z11;
        float perm1 = z01 + z10;
        float n0, n1;
        if (perm0 >= perm1) { n0 = z00; n1 = z11; }
        else               { n0 = z01; n1 = z10; }
        float d0 = den_z[0 * BATCH + b];
        float d1 = den_z[1 * BATCH + b];
        l = -(n0 - d0) - (n1 - d1);
    }
    #pragma unroll
    for (int o = 32; o > 0; o >>= 1) l += __shfl_down(l, o, 64);
    if (tid == 0) out[0] = l;
}

// ---------------------------------------------------------------------------
extern "C" void kernel_launch(void* const* d_in, const int* in_sizes, int n_in,
                              void* d_out, int out_size, void* d_ws, size_t ws_size,
                              hipStream_t stream) {
    const float* est       = (const float*)d_in[0];
    const int*   seqlen    = (const int*)d_in[1];
    const int*   num_src   = (const int*)d_in[2];
    const int*   num_dst   = (const int*)d_in[3];
    const int*   num_label = (const int*)d_in[4];
    const float* num_weight= (const float*)d_in[5];
    const float* num_start = (const float*)d_in[6];
    const float* num_final = (const float*)d_in[7];
    const int*   den_src   = (const int*)d_in[8];
    const int*   den_dst   = (const int*)d_in[9];
    const int*   den_label = (const int*)d_in[10];
    const float* den_weight= (const float*)d_in[11];
    const float* den_start = (const float*)d_in[12];
    const float* den_final = (const float*)d_in[13];

    char* ws = (char*)d_ws;
    const int nNumArcsTot = S_SPK * BATCH * NUM_ARCS;  // 38400
    int4*  den_p = (int4*)ws;                               // 960000 B
    int4*  num_p = (int4*)(ws + 960000);                    // 614400 B
    float* den_z = (float*)(ws + 1574400);                  // 32 floats
    float* num_z = (float*)(ws + 1574528);                  // 64 floats

    pack_arcs<<<(DEN_ARCS + 255) / 256, 256, 0, stream>>>(
        den_src, den_dst, den_label, den_weight, den_p, DEN_ARCS);
    pack_arcs<<<(nNumArcsTot + 255) / 256, 256, 0, stream>>>(
        num_src, num_dst, num_label, num_weight, num_p, nNumArcsTot);

    forward_kernel<<<S_SPK * BATCH + S_SPK * S_SPK * BATCH, 1024, 0, stream>>>(
        est, seqlen, den_p, den_start, den_final,
        num_p, num_start, num_final, den_z, num_z);

    loss_kernel<<<1, 64, 0, stream>>>(den_z, num_z, (float*)d_out);
}

// Round 2
// 3327.873 us; speedup vs baseline: 7.4876x; 7.4876x over previous
//
#include <hip/hip_runtime.h>
#include <hip/hip_bf16.h>

#define S_SPK 2
#define BATCH 16
#define TMAX 300
#define CLASSES 3000
#define NUM_STATES 400
#define NUM_ARCS 1200
#define DEN_STATES 3000
#define DEN_ARCS 60000

#define DEN_GROUPS 1000      // 3 states per thread
#define DEN_CAP    63000     // 60000 + 3*1000 pad worst case
#define NUM_CAP_G  2400      // per graph: 1200 + 3*400
#define NGRAPH     32        // (p,b) graphs

// ---------------- workspace layout (bytes) ----------------
#define WS_DEN_ARCS   0                         // 63000 * 8  = 504000
#define WS_NUM_ARCS   504000                    // 32*2400*8  = 614400
#define WS_DEN_CNT    1118400                   // 3000*4     = 12000
#define WS_DEN_R      1130400                   // 3001*4     = 12004 (pad)
#define WS_DEN_CUR    1142416                   // 3000*4     = 12000
#define WS_NUM_CNT    1154416                   // 32*400*4   = 51200
#define WS_NUM_R      1205616                   // 32*401*4   = 51328
#define WS_NUM_CUR    1256944                   // 32*400*4   = 51200
#define WS_DEN_Z      1308144                   // 32 floats
#define WS_NUM_Z      1308272                   // 64 floats
#define WS_ZERO_INTS  (1308144/4)               // zero everything below den_z

// ---------------------------------------------------------------------------
__global__ void zero_ws(int* __restrict__ p, int n) {
    int i = blockIdx.x * blockDim.x + threadIdx.x;
    for (; i < n; i += gridDim.x * blockDim.x) p[i] = 0;
}

__global__ void hist_den(const int* __restrict__ dst, int* __restrict__ cnt) {
    int i = blockIdx.x * blockDim.x + threadIdx.x;
    if (i < DEN_ARCS) atomicAdd(&cnt[dst[i]], 1);
}

__global__ void hist_num(const int* __restrict__ dst, int* __restrict__ cnt) {
    int i = blockIdx.x * blockDim.x + threadIdx.x;
    if (i < NGRAPH * NUM_ARCS) {
        int g = i / NUM_ARCS;
        atomicAdd(&cnt[g * NUM_STATES + dst[i]], 1);
    }
}

// one block, 1024 threads: padded group prefix for den CSR
__global__ void scan_den(const int* __restrict__ cnt, int* __restrict__ R) {
    __shared__ int sc[1024];
    int tid = threadIdx.x;
    int c0 = 0, c1 = 0, c2 = 0, pg = 0;
    if (tid < DEN_GROUPS) {
        c0 = cnt[3 * tid]; c1 = cnt[3 * tid + 1]; c2 = cnt[3 * tid + 2];
        pg = (c0 + c1 + c2 + 3) & ~3;
    }
    sc[tid] = pg; __syncthreads();
    for (int o = 1; o < 1024; o <<= 1) {
        int v = (tid >= o) ? sc[tid - o] : 0;
        __syncthreads(); sc[tid] += v; __syncthreads();
    }
    int ex = sc[tid] - pg;
    if (tid < DEN_GROUPS) {
        R[3 * tid] = ex; R[3 * tid + 1] = ex + c0; R[3 * tid + 2] = ex + c0 + c1;
    }
    if (tid == DEN_GROUPS) R[3 * DEN_GROUPS] = ex;  // total
}

// 32 blocks x 512: per-graph padded per-state prefix
__global__ void scan_num(const int* __restrict__ cnt, int* __restrict__ R) {
    __shared__ int sc[512];
    int g = blockIdx.x, tid = threadIdx.x;
    int c = 0, pg = 0;
    if (tid < NUM_STATES) { c = cnt[g * NUM_STATES + tid]; pg = (c + 3) & ~3; }
    sc[tid] = pg; __syncthreads();
    for (int o = 1; o < 512; o <<= 1) {
        int v = (tid >= o) ? sc[tid - o] : 0;
        __syncthreads(); sc[tid] += v; __syncthreads();
    }
    int ex = sc[tid] - pg;
    if (tid <= NUM_STATES) R[g * (NUM_STATES + 1) + tid] = ex;
}

__global__ void scat_den(const int* __restrict__ src, const int* __restrict__ dst,
                         const int* __restrict__ lab, const float* __restrict__ w,
                         const int* __restrict__ R, int* __restrict__ cur,
                         int2* __restrict__ out) {
    int i = blockIdx.x * blockDim.x + threadIdx.x;
    if (i >= DEN_ARCS) return;
    int d = dst[i];
    int pos = R[d] + atomicAdd(&cur[d], 1);
    out[pos] = make_int2(src[i] | (lab[i] << 16), __float_as_int(__expf(w[i])));
}

__global__ void scat_num(const int* __restrict__ src, const int* __restrict__ dst,
                         const int* __restrict__ lab, const float* __restrict__ w,
                         const int* __restrict__ R, int* __restrict__ cur,
                         int2* __restrict__ out) {
    int i = blockIdx.x * blockDim.x + threadIdx.x;
    if (i >= NGRAPH * NUM_ARCS) return;
    int g = i / NUM_ARCS;
    int d = dst[i];
    int pos = R[g * (NUM_STATES + 1) + d] + atomicAdd(&cur[g * NUM_STATES + d], 1);
    out[g * NUM_CAP_G + pos] =
        make_int2(src[i] | (lab[i] << 16), __float_as_int(__expf(w[i])));
}

// ---------------------------------------------------------------------------
// Forward in probability domain with per-step rescale folded into p staging.
// CSR-by-dst gather: each thread owns SPT states, accumulates in registers.
// ---------------------------------------------------------------------------
template<int SPT>
__device__ __forceinline__ void fsa_fwd(
    int nStates, int groups, const int* __restrict__ R,
    const int2* __restrict__ arcs,
    const float* __restrict__ start, const float* __restrict__ fin,
    const float* __restrict__ est, int L, float* __restrict__ out,
    float* A0, float* A1, float* p, float* red)
{
    const int tid = threadIdx.x, lane = tid & 63, wid = tid >> 6;

    for (int j = tid; j < nStates; j += 1024) A0[j] = __expf(start[j]);

    int rs = 0, b1 = 0, b2 = 0, re = 0;
    if (tid < groups) {
        if (SPT == 3) { rs = R[3*tid]; b1 = R[3*tid+1]; b2 = R[3*tid+2]; re = R[3*tid+3]; }
        else          { rs = R[tid];   re = R[tid+1];   b1 = re; b2 = re; }
    }
    const int j0 = tid, j1 = tid + 1024, j2 = tid + 2048;
    float l0 = 0.f, l1 = 0.f, l2 = 0.f;
    if (j0 < CLASSES) l0 = est[j0];
    if (j1 < CLASSES) l1 = est[j1];
    if (j2 < CLASSES) l2 = est[j2];

    float c = 1.f, OFF = 0.f, pend = 0.f;
    const int4* arcs4 = (const int4*)arcs;

    for (int t = 0; t < L; ++t) {
        OFF += pend;
        // stage p = exp(llh)*c ; prefetch next row into registers
        if (j0 < CLASSES) p[j0] = __expf(l0) * c;
        if (j1 < CLASSES) p[j1] = __expf(l1) * c;
        if (j2 < CLASSES) p[j2] = __expf(l2) * c;
        {
            const float* nr = est + (size_t)((t + 1 < L) ? (t + 1) : t) * CLASSES;
            if (j0 < CLASSES) l0 = nr[j0];
            if (j1 < CLASSES) l1 = nr[j1];
            if (j2 < CLASSES) l2 = nr[j2];
        }
        __syncthreads();   // p ready; prev-step buffers settled

        const float* Ac = (t & 1) ? A1 : A0;
        float*       An = (t & 1) ? A0 : A1;
        float a0 = 0.f, a1 = 0.f, a2 = 0.f;
        for (int r = rs; r < re; r += 4) {
            int4 q0 = arcs4[(r >> 1)];
            int4 q1 = arcs4[(r >> 1) + 1];
            float v0 = Ac[q0.x & 0xffff] * p[((unsigned)q0.x) >> 16] * __int_as_float(q0.y);
            float v1 = Ac[q0.z & 0xffff] * p[((unsigned)q0.z) >> 16] * __int_as_float(q0.w);
            float v2 = Ac[q1.x & 0xffff] * p[((unsigned)q1.x) >> 16] * __int_as_float(q1.y);
            float v3 = Ac[q1.z & 0xffff] * p[((unsigned)q1.z) >> 16] * __int_as_float(q1.w);
            if (SPT == 3) {
                a0 += (r     < b1 ? v0 : 0.f); a1 += (r     >= b1 && r     < b2 ? v0 : 0.f); a2 += (r     >= b2 ? v0 : 0.f);
                a0 += (r + 1 < b1 ? v1 : 0.f); a1 += (r + 1 >= b1 && r + 1 < b2 ? v1 : 0.f); a2 += (r + 1 >= b2 ? v1 : 0.f);
                a0 += (r + 2 < b1 ? v2 : 0.f); a1 += (r + 2 >= b1 && r + 2 < b2 ? v2 : 0.f); a2 += (r + 2 >= b2 ? v2 : 0.f);
                a0 += (r + 3 < b1 ? v3 : 0.f); a1 += (r + 3 >= b1 && r + 3 < b2 ? v3 : 0.f); a2 += (r + 3 >= b2 ? v3 : 0.f);
            } else {
                a0 += v0 + v1 + v2 + v3;
            }
        }
        float mymax = 0.f;
        if (tid < groups) {
            if (SPT == 3) {
                An[3*tid] = a0; An[3*tid+1] = a1; An[3*tid+2] = a2;
                mymax = fmaxf(fmaxf(a0, a1), a2);
            } else { An[tid] = a0; mymax = a0; }
        }
        #pragma unroll
        for (int o = 32; o > 0; o >>= 1) mymax = fmaxf(mymax, __shfl_down(mymax, o, 64));
        if (lane == 0) red[wid] = mymax;
        __syncthreads();
        if (tid < 64) {
            float v = (tid < 16) ? red[tid] : 0.f;
            #pragma unroll
            for (int o = 8; o > 0; o >>= 1) v = fmaxf(v, __shfl_down(v, o, 64));
            if (tid == 0) red[0] = v;
        }
        __syncthreads();
        float M = fmaxf(red[0], 1e-37f);
        c = 1.0f / M;
        pend = __logf(M);
    }

    const float* Af = (L & 1) ? A1 : A0;
    float fs = 0.f;
    for (int j = tid; j < nStates; j += 1024) fs += Af[j] * __expf(fin[j]);
    __syncthreads();   // protect red[] (everyone has read M)
    #pragma unroll
    for (int o = 32; o > 0; o >>= 1) fs += __shfl_down(fs, o, 64);
    if (lane == 0) red[wid] = fs;
    __syncthreads();
    if (tid == 0) {
        float s = 0.f;
        #pragma unroll
        for (int k = 0; k < 16; ++k) s += red[k];
        out[0] = OFF + __logf(s);
    }
}

__global__ __launch_bounds__(1024) void forward_kernel(
    const float* __restrict__ est, const int* __restrict__ seqlen,
    const int2* __restrict__ den_arcs, const int* __restrict__ den_R,
    const float* __restrict__ den_start, const float* __restrict__ den_final,
    const int2* __restrict__ num_arcs, const int* __restrict__ num_R,
    const float* __restrict__ num_start, const float* __restrict__ num_final,
    float* __restrict__ den_z, float* __restrict__ num_z)
{
    __shared__ float A0[DEN_STATES];
    __shared__ float A1[DEN_STATES];
    __shared__ float p[CLASSES];
    __shared__ float red[16];

    int blk = blockIdx.x;
    if (blk < S_SPK * BATCH) {
        int b = blk & 15;
        int L = seqlen[b];
        fsa_fwd<3>(DEN_STATES, DEN_GROUPS, den_R, den_arcs,
                   den_start, den_final,
                   est + (size_t)blk * TMAX * CLASSES, L, &den_z[blk],
                   A0, A1, p, red);
    } else {
        int q = blk - S_SPK * BATCH;
        int b = q & 15;
        int sp = q >> 4;
        int s = sp >> 1, pp = sp & 1;
        int L = seqlen[b];
        int g = pp * BATCH + b;
        fsa_fwd<1>(NUM_STATES, NUM_STATES,
                   num_R + (size_t)g * (NUM_STATES + 1),
                   num_arcs + (size_t)g * NUM_CAP_G,
                   num_start + (size_t)g * NUM_STATES,
                   num_final + (size_t)g * NUM_STATES,
                   est + (size_t)(s * BATCH + b) * TMAX * CLASSES, L, &num_z[q],
                   A0, A1, p, red);
    }
}

// ---------------------------------------------------------------------------
__global__ void loss_kernel(const float* __restrict__ den_z,
                            const float* __restrict__ num_z,
                            float* __restrict__ out)
{
    int tid = threadIdx.x;
    float l = 0.f;
    if (tid < BATCH) {
        int b = tid;
        float z00 = num_z[(0 * 2 + 0) * BATCH + b];
        float z01 = num_z[(0 * 2 + 1) * BATCH + b];
        float z10 = num_z[(1 * 2 + 0) * BATCH + b];
        float z11 = num_z[(1 * 2 + 1) * BATCH + b];
        float perm0 = z00 + z11;
        float perm1 = z01 + z10;
        float n0, n1;
        if (perm0 >= perm1) { n0 = z00; n1 = z11; }
        else                { n0 = z01; n1 = z10; }
        l = -(n0 - den_z[0 * BATCH + b]) - (n1 - den_z[1 * BATCH + b]);
    }
    #pragma unroll
    for (int o = 32; o > 0; o >>= 1) l += __shfl_down(l, o, 64);
    if (tid == 0) out[0] = l;
}

// ---------------------------------------------------------------------------
extern "C" void kernel_launch(void* const* d_in, const int* in_sizes, int n_in,
                              void* d_out, int out_size, void* d_ws, size_t ws_size,
                              hipStream_t stream) {
    const float* est        = (const float*)d_in[0];
    const int*   seqlen     = (const int*)d_in[1];
    const int*   num_src    = (const int*)d_in[2];
    const int*   num_dst    = (const int*)d_in[3];
    const int*   num_label  = (const int*)d_in[4];
    const float* num_weight = (const float*)d_in[5];
    const float* num_start  = (const float*)d_in[6];
    const float* num_final  = (const float*)d_in[7];
    const int*   den_src    = (const int*)d_in[8];
    const int*   den_dst    = (const int*)d_in[9];
    const int*   den_label  = (const int*)d_in[10];
    const float* den_weight = (const float*)d_in[11];
    const float* den_start  = (const float*)d_in[12];
    const float* den_final  = (const float*)d_in[13];

    char* ws = (char*)d_ws;
    int2* den_arcs = (int2*)(ws + WS_DEN_ARCS);
    int2* num_arcs = (int2*)(ws + WS_NUM_ARCS);
    int*  den_cnt  = (int*)(ws + WS_DEN_CNT);
    int*  den_R    = (int*)(ws + WS_DEN_R);
    int*  den_cur  = (int*)(ws + WS_DEN_CUR);
    int*  num_cnt  = (int*)(ws + WS_NUM_CNT);
    int*  num_R    = (int*)(ws + WS_NUM_R);
    int*  num_cur  = (int*)(ws + WS_NUM_CUR);
    float* den_z   = (float*)(ws + WS_DEN_Z);
    float* num_z   = (float*)(ws + WS_NUM_Z);

    zero_ws<<<512, 256, 0, stream>>>((int*)ws, WS_ZERO_INTS);
    hist_den<<<(DEN_ARCS + 255) / 256, 256, 0, stream>>>(den_dst, den_cnt);
    hist_num<<<(NGRAPH * NUM_ARCS + 255) / 256, 256, 0, stream>>>(num_dst, num_cnt);
    scan_den<<<1, 1024, 0, stream>>>(den_cnt, den_R);
    scan_num<<<NGRAPH, 512, 0, stream>>>(num_cnt, num_R);
    scat_den<<<(DEN_ARCS + 255) / 256, 256, 0, stream>>>(
        den_src, den_dst, den_label, den_weight, den_R, den_cur, den_arcs);
    scat_num<<<(NGRAPH * NUM_ARCS + 255) / 256, 256, 0, stream>>>(
        num_src, num_dst, num_label, num_weight, num_R, num_cur, num_arcs);

    forward_kernel<<<S_SPK * BATCH + S_SPK * S_SPK * BATCH, 1024, 0, stream>>>(
        est, seqlen, den_arcs, den_R, den_start, den_final,
        num_arcs, num_R, num_start, num_final, den_z, num_z);

    loss_kernel<<<1, 64, 0, stream>>>(den_z, num_z, (float*)d_out);
}

// Round 3
// 2545.274 us; speedup vs baseline: 9.7898x; 1.3075x over previous
//
#include <hip/hip_runtime.h>
#include <hip/hip_bf16.h>

#define S_SPK 2
#define BATCH 16
#define TMAX 300
#define CLASSES 3000
#define NUM_STATES 400
#define NUM_ARCS 1200
#define DEN_STATES 3000
#define DEN_ARCS 60000
#define NEGF -1e30f

#define KCH 6                 // den chunks per sequence
#define CHSTATES 500          // 3000 / 6
#define NSEQ 32               // S_SPK * BATCH
#define DEN_CAP 72000         // 60000 + 4*3000 per-state pad worst case
#define NUM_CAP_G 2400        // per graph: 1200 + 3*400
#define NGRAPH 32             // (p,b) graphs

// ---------------- workspace layout (bytes) ----------------
#define WS_DEN_ARCS   0              // 72000*8   = 576000
#define WS_NUM_ARCS   576000         // 32*2400*8 = 614400 -> 1190400
#define WS_DEN_CNT    1190400        // 3000*4    -> 1202400
#define WS_DEN_R      1202400        // 3001*4    -> 1214416 (pad)
#define WS_DEN_CUR    1214416        // 3000*4    -> 1226416
#define WS_NUM_CNT    1226416        // 32*400*4  -> 1277616
#define WS_NUM_R      1277616        // 32*401*4  -> 1328944
#define WS_NUM_CUR    1328944        // 32*400*4  -> 1380144
#define WS_GALPHA     1380144        // 32*2*3000*4 = 768000 -> 2148144
#define WS_GMAX       2148144        // 32*2*8*4  = 2048 -> 2150192
#define WS_CNT        2150192        // 32*4      -> 2150320
#define WS_PERM       2150320        // 3000*4    -> 2162320
#define WS_DEN_Z      2162320        // 32 floats -> 2162448
#define WS_NUM_Z      2162448        // 64 floats -> 2162704
#define WS_ZERO_INTS  (2162320 / 4)  // zero everything below den_z

// ---------------------------------------------------------------------------
__global__ void zero_ws(int* __restrict__ p, int n) {
    int i = blockIdx.x * blockDim.x + threadIdx.x;
    for (; i < n; i += gridDim.x * blockDim.x) p[i] = 0;
}

__global__ void hist_den(const int* __restrict__ dst, int* __restrict__ cnt) {
    int i = blockIdx.x * blockDim.x + threadIdx.x;
    if (i < DEN_ARCS) atomicAdd(&cnt[dst[i]], 1);
}

__global__ void hist_num(const int* __restrict__ dst, int* __restrict__ cnt) {
    int i = blockIdx.x * blockDim.x + threadIdx.x;
    if (i < NGRAPH * NUM_ARCS) {
        int g = i / NUM_ARCS;
        atomicAdd(&cnt[g * NUM_STATES + dst[i]], 1);
    }
}

// one block, 1024 threads: per-STATE x4-padded prefix for den CSR
__global__ void scan_den(const int* __restrict__ cnt, int* __restrict__ R) {
    __shared__ int sc[1024];
    int tid = threadIdx.x;
    int c0 = 0, c1 = 0, c2 = 0, p0 = 0, p1 = 0, p2 = 0, pg = 0;
    if (tid < 1000) {
        c0 = cnt[3 * tid]; c1 = cnt[3 * tid + 1]; c2 = cnt[3 * tid + 2];
        p0 = (c0 + 3) & ~3; p1 = (c1 + 3) & ~3; p2 = (c2 + 3) & ~3;
        pg = p0 + p1 + p2;
    }
    sc[tid] = pg; __syncthreads();
    for (int o = 1; o < 1024; o <<= 1) {
        int v = (tid >= o) ? sc[tid - o] : 0;
        __syncthreads(); sc[tid] += v; __syncthreads();
    }
    int ex = sc[tid] - pg;
    if (tid < 1000) {
        R[3 * tid] = ex; R[3 * tid + 1] = ex + p0; R[3 * tid + 2] = ex + p0 + p1;
    }
    if (tid == 1000) R[3000] = ex;  // total
}

// 32 blocks x 512: per-graph padded per-state prefix (num)
__global__ void scan_num(const int* __restrict__ cnt, int* __restrict__ R) {
    __shared__ int sc[512];
    int g = blockIdx.x, tid = threadIdx.x;
    int c = 0, pg = 0;
    if (tid < NUM_STATES) { c = cnt[g * NUM_STATES + tid]; pg = (c + 3) & ~3; }
    sc[tid] = pg; __syncthreads();
    for (int o = 1; o < 512; o <<= 1) {
        int v = (tid >= o) ? sc[tid - o] : 0;
        __syncthreads(); sc[tid] += v; __syncthreads();
    }
    int ex = sc[tid] - pg;
    if (tid <= NUM_STATES) R[g * (NUM_STATES + 1) + tid] = ex;
}

// per-chunk counting sort of states by arc count -> wave load balancing
__global__ void sort_states(const int* __restrict__ cnt, int* __restrict__ perm) {
    __shared__ int hist[128], hbase[128];
    int c = blockIdx.x, tid = threadIdx.x;  // 512 threads
    if (tid < 128) hist[tid] = 0;
    __syncthreads();
    int st = -1, k = 0;
    if (tid < CHSTATES) {
        st = c * CHSTATES + tid;
        k = min(cnt[st], 127);
        atomicAdd(&hist[k], 1);
    }
    __syncthreads();
    if (tid == 0) { int run = 0; for (int i = 0; i < 128; i++) { hbase[i] = run; run += hist[i]; } }
    __syncthreads();
    if (tid < 128) hist[tid] = 0;
    __syncthreads();
    if (tid < CHSTATES) {
        int pos = hbase[k] + atomicAdd(&hist[k], 1);
        perm[c * CHSTATES + pos] = st;
    }
}

__global__ void scat_den(const int* __restrict__ src, const int* __restrict__ dst,
                         const int* __restrict__ lab, const float* __restrict__ w,
                         const int* __restrict__ R, int* __restrict__ cur,
                         int2* __restrict__ out) {
    int i = blockIdx.x * blockDim.x + threadIdx.x;
    if (i >= DEN_ARCS) return;
    int d = dst[i];
    int pos = R[d] + atomicAdd(&cur[d], 1);
    out[pos] = make_int2(src[i] | (lab[i] << 16), __float_as_int(__expf(w[i])));
}

__global__ void scat_num(const int* __restrict__ src, const int* __restrict__ dst,
                         const int* __restrict__ lab, const float* __restrict__ w,
                         const int* __restrict__ R, int* __restrict__ cur,
                         int2* __restrict__ out) {
    int i = blockIdx.x * blockDim.x + threadIdx.x;
    if (i >= NGRAPH * NUM_ARCS) return;
    int g = i / NUM_ARCS;
    int d = dst[i];
    int pos = R[g * (NUM_STATES + 1) + d] + atomicAdd(&cur[g * NUM_STATES + d], 1);
    out[g * NUM_CAP_G + pos] =
        make_int2(src[i] | (lab[i] << 16), __float_as_int(__expf(w[i])));
}

// ---------------------------------------------------------------------------
// num forward (round-2 verified path): single block, prob domain, SPT=1
// ---------------------------------------------------------------------------
__device__ __forceinline__ void num_fwd(
    const int* __restrict__ R, const int2* __restrict__ arcs,
    const float* __restrict__ start, const float* __restrict__ fin,
    const float* __restrict__ est, int L, float* __restrict__ out,
    float* A0, float* A1, float* p, float* red)
{
    const int tid = threadIdx.x, lane = tid & 63, wid = tid >> 6;

    for (int j = tid; j < NUM_STATES; j += 1024) A0[j] = __expf(start[j]);

    int rs = 0, re = 0;
    if (tid < NUM_STATES) { rs = R[tid]; re = R[tid + 1]; }
    const int j0 = tid, j1 = tid + 1024, j2 = tid + 2048;
    float l0 = 0.f, l1 = 0.f, l2 = 0.f;
    if (j0 < CLASSES) l0 = est[j0];
    if (j1 < CLASSES) l1 = est[j1];
    if (j2 < CLASSES) l2 = est[j2];

    float c = 1.f, OFF = 0.f, pend = 0.f;
    const int4* arcs4 = (const int4*)arcs;

    for (int t = 0; t < L; ++t) {
        OFF += pend;
        if (j0 < CLASSES) p[j0] = __expf(l0) * c;
        if (j1 < CLASSES) p[j1] = __expf(l1) * c;
        if (j2 < CLASSES) p[j2] = __expf(l2) * c;
        {
            const float* nr = est + (size_t)((t + 1 < L) ? (t + 1) : t) * CLASSES;
            if (j0 < CLASSES) l0 = nr[j0];
            if (j1 < CLASSES) l1 = nr[j1];
            if (j2 < CLASSES) l2 = nr[j2];
        }
        __syncthreads();

        const float* Ac = (t & 1) ? A1 : A0;
        float*       An = (t & 1) ? A0 : A1;
        float a0 = 0.f;
        for (int r = rs; r < re; r += 4) {
            int4 q0 = arcs4[(r >> 1)];
            int4 q1 = arcs4[(r >> 1) + 1];
            a0 += Ac[q0.x & 0xffff] * p[((unsigned)q0.x) >> 16] * __int_as_float(q0.y);
            a0 += Ac[q0.z & 0xffff] * p[((unsigned)q0.z) >> 16] * __int_as_float(q0.w);
            a0 += Ac[q1.x & 0xffff] * p[((unsigned)q1.x) >> 16] * __int_as_float(q1.y);
            a0 += Ac[q1.z & 0xffff] * p[((unsigned)q1.z) >> 16] * __int_as_float(q1.w);
        }
        float mymax = 0.f;
        if (tid < NUM_STATES) { An[tid] = a0; mymax = a0; }
        #pragma unroll
        for (int o = 32; o > 0; o >>= 1) mymax = fmaxf(mymax, __shfl_down(mymax, o, 64));
        if (lane == 0) red[wid] = mymax;
        __syncthreads();
        if (tid < 64) {
            float v = (tid < 16) ? red[tid] : 0.f;
            #pragma unroll
            for (int o = 8; o > 0; o >>= 1) v = fmaxf(v, __shfl_down(v, o, 64));
            if (tid == 0) red[0] = v;
        }
        __syncthreads();
        float M = fmaxf(red[0], 1e-37f);
        c = 1.0f / M;
        pend = __logf(M);
    }

    const float* Af = (L & 1) ? A1 : A0;
    float fs = 0.f;
    for (int j = tid; j < NUM_STATES; j += 1024) fs += Af[j] * __expf(fin[j]);
    __syncthreads();
    #pragma unroll
    for (int o = 32; o > 0; o >>= 1) fs += __shfl_down(fs, o, 64);
    if (lane == 0) red[wid] = fs;
    __syncthreads();
    if (tid == 0) {
        float s = 0.f;
        #pragma unroll
        for (int k = 0; k < 16; ++k) s += red[k];
        out[0] = OFF + __logf(s);
    }
}

// ---------------------------------------------------------------------------
// Fused forward: blocks [0,192) = den chunk*32+seq; [192,256) = num.
// Den: k=6 chunks exchange alpha per step via L3 (agent-scope atomics).
// ---------------------------------------------------------------------------
__global__ __launch_bounds__(1024) void forward_kernel(
    const float* __restrict__ est, const int* __restrict__ seqlen,
    const int2* __restrict__ den_arcs, const int* __restrict__ den_R,
    const float* __restrict__ den_start, const float* __restrict__ den_final,
    const int2* __restrict__ num_arcs, const int* __restrict__ num_R,
    const float* __restrict__ num_start, const float* __restrict__ num_final,
    const int* __restrict__ perm, float* __restrict__ galpha,
    float* __restrict__ gmax, unsigned* __restrict__ cnt,
    float* __restrict__ den_z, float* __restrict__ num_z)
{
    __shared__ float S1[DEN_STATES];   // den: alpha_prev (full) | num: A0
    __shared__ float S2[CLASSES];      // p
    __shared__ float S3[512];          // den: own-slice staging | num: A1
    __shared__ float red[18];

    const int blk = blockIdx.x;
    const int tid = threadIdx.x, lane = tid & 63, wid = tid >> 6;

    if (blk < KCH * NSEQ) {
        const int seq = blk & 31;        // blk = chunk*32 + seq -> chunks share XCD
        const int chunk = blk >> 5;
        const int b = seq & 15;
        const int L = seqlen[b];
        const float* est_base = est + (size_t)seq * TMAX * CLASSES;
        const int base = chunk * CHSTATES;

        int rs = 0, re = 0, loc = 0;
        if (tid < CHSTATES) {
            int st = perm[base + tid];
            loc = st - base;
            rs = den_R[st]; re = den_R[st + 1];
        }
        const int j0 = tid, j1 = tid + 1024, j2 = tid + 2048;
        float l0 = 0.f, l1 = 0.f, l2 = 0.f;
        if (j0 < CLASSES) l0 = est_base[j0];
        if (j1 < CLASSES) l1 = est_base[j1];
        if (j2 < CLASSES) l2 = est_base[j2];

        float OFF = 0.f;
        unsigned* cptr = &cnt[seq];
        const int4* arcs4 = (const int4*)den_arcs;

        for (int t = 0; t < L; ++t) {
            // stage p_raw = exp(llh) (no scale: scale factors out of the sum)
            if (j0 < CLASSES) S2[j0] = __expf(l0);
            if (j1 < CLASSES) S2[j1] = __expf(l1);
            if (j2 < CLASSES) S2[j2] = __expf(l2);
            {
                const float* nr = est_base + (size_t)((t + 1 < L) ? (t + 1) : t) * CLASSES;
                if (j0 < CLASSES) l0 = nr[j0];
                if (j1 < CLASSES) l1 = nr[j1];
                if (j2 < CLASSES) l2 = nr[j2];
            }
            if (t == 0) {
                if (j0 < DEN_STATES) S1[j0] = __expf(den_start[j0]);
                if (j1 < DEN_STATES) S1[j1] = __expf(den_start[j1]);
                if (j2 < DEN_STATES) S1[j2] = __expf(den_start[j2]);
                if (tid == 0) red[16] = 1.0f;
                __syncthreads();                               // A
            } else {
                if (tid == 0) {
                    unsigned tgt = (unsigned)(KCH * t);
                    while (__hip_atomic_load(cptr, __ATOMIC_ACQUIRE,
                                             __HIP_MEMORY_SCOPE_AGENT) < tgt)
                        __builtin_amdgcn_s_sleep(2);
                    const float* gm = gmax + ((size_t)seq * 2 + ((t - 1) & 1)) * 8;
                    float M = 1e-37f;
                    #pragma unroll
                    for (int c2 = 0; c2 < KCH; c2++)
                        M = fmaxf(M, __hip_atomic_load(&gm[c2], __ATOMIC_RELAXED,
                                                       __HIP_MEMORY_SCOPE_AGENT));
                    red[16] = 1.0f / M;
                    OFF += __logf(M);
                }
                __syncthreads();                               // A
                const float* gaP = galpha + ((size_t)seq * 2 + ((t - 1) & 1)) * DEN_STATES;
                float x0 = 0.f, x1 = 0.f, x2 = 0.f;
                if (j0 < DEN_STATES) x0 = __hip_atomic_load(&gaP[j0], __ATOMIC_RELAXED, __HIP_MEMORY_SCOPE_AGENT);
                if (j1 < DEN_STATES) x1 = __hip_atomic_load(&gaP[j1], __ATOMIC_RELAXED, __HIP_MEMORY_SCOPE_AGENT);
                if (j2 < DEN_STATES) x2 = __hip_atomic_load(&gaP[j2], __ATOMIC_RELAXED, __HIP_MEMORY_SCOPE_AGENT);
                if (j0 < DEN_STATES) S1[j0] = x0;
                if (j1 < DEN_STATES) S1[j1] = x1;
                if (j2 < DEN_STATES) S1[j2] = x2;
                __syncthreads();                               // B
            }

            const float cM = red[16];
            float acc = 0.f;
            for (int r = rs; r < re; r += 4) {
                int4 q0 = arcs4[(r >> 1)];
                int4 q1 = arcs4[(r >> 1) + 1];
                acc += S1[q0.x & 0xffff] * S2[((unsigned)q0.x) >> 16] * __int_as_float(q0.y);
                acc += S1[q0.z & 0xffff] * S2[((unsigned)q0.z) >> 16] * __int_as_float(q0.w);
                acc += S1[q1.x & 0xffff] * S2[((unsigned)q1.x) >> 16] * __int_as_float(q1.y);
                acc += S1[q1.z & 0xffff] * S2[((unsigned)q1.z) >> 16] * __int_as_float(q1.w);
            }
            float val = acc * cM;
            float mymax = 0.f;
            if (tid < CHSTATES) { S3[loc] = val; mymax = val; }
            #pragma unroll
            for (int o = 32; o > 0; o >>= 1) mymax = fmaxf(mymax, __shfl_down(mymax, o, 64));
            if (lane == 0) red[wid] = mymax;
            __syncthreads();                                   // C0: S3 + red ready

            float* gaW = galpha + ((size_t)seq * 2 + (t & 1)) * DEN_STATES;
            if (tid < CHSTATES)
                __hip_atomic_store(&gaW[base + tid], S3[tid], __ATOMIC_RELAXED,
                                   __HIP_MEMORY_SCOPE_AGENT);
            float Msl = 0.f;
            if (tid < 64) {
                float v = (tid < 16) ? red[tid] : 0.f;
                #pragma unroll
                for (int o = 8; o > 0; o >>= 1) v = fmaxf(v, __shfl_down(v, o, 64));
                Msl = v;
            }
            __syncthreads();                                   // C1: ga stores drained
            if (tid == 0) {
                float* gm = gmax + ((size_t)seq * 2 + (t & 1)) * 8;
                __hip_atomic_store(&gm[chunk], Msl, __ATOMIC_RELAXED,
                                   __HIP_MEMORY_SCOPE_AGENT);
                __hip_atomic_fetch_add(cptr, 1u, __ATOMIC_RELEASE,
                                       __HIP_MEMORY_SCOPE_AGENT);
            }
        }

        // epilogue: chunk 0 computes logZ from final slices
        if (chunk == 0) {
            if (tid == 0) {
                unsigned tgt = (unsigned)(KCH * L);
                while (__hip_atomic_load(cptr, __ATOMIC_ACQUIRE,
                                         __HIP_MEMORY_SCOPE_AGENT) < tgt)
                    __builtin_amdgcn_s_sleep(2);
            }
            __syncthreads();
            const float* gaF = galpha + ((size_t)seq * 2 + ((L - 1) & 1)) * DEN_STATES;
            float fs = 0.f;
            if (j0 < DEN_STATES)
                fs += __hip_atomic_load(&gaF[j0], __ATOMIC_RELAXED, __HIP_MEMORY_SCOPE_AGENT) * __expf(den_final[j0]);
            if (j1 < DEN_STATES)
                fs += __hip_atomic_load(&gaF[j1], __ATOMIC_RELAXED, __HIP_MEMORY_SCOPE_AGENT) * __expf(den_final[j1]);
            if (j2 < DEN_STATES)
                fs += __hip_atomic_load(&gaF[j2], __ATOMIC_RELAXED, __HIP_MEMORY_SCOPE_AGENT) * __expf(den_final[j2]);
            #pragma unroll
            for (int o = 32; o > 0; o >>= 1) fs += __shfl_down(fs, o, 64);
            if (lane == 0) red[wid] = fs;
            __syncthreads();
            if (tid == 0) {
                float s = 0.f;
                #pragma unroll
                for (int k = 0; k < 16; ++k) s += red[k];
                den_z[seq] = OFF + __logf(s);
            }
        }
    } else {
        const int q = blk - KCH * NSEQ;
        const int b = q & 15;
        const int sp = q >> 4;
        const int s = sp >> 1, pp = sp & 1;
        const int L = seqlen[b];
        const int g = pp * BATCH + b;
        num_fwd(num_R + (size_t)g * (NUM_STATES + 1),
                num_arcs + (size_t)g * NUM_CAP_G,
                num_start + (size_t)g * NUM_STATES,
                num_final + (size_t)g * NUM_STATES,
                est + (size_t)(s * BATCH + b) * TMAX * CLASSES, L, &num_z[q],
                S1, S3, S2, red);
    }
}

// ---------------------------------------------------------------------------
__global__ void loss_kernel(const float* __restrict__ den_z,
                            const float* __restrict__ num_z,
                            float* __restrict__ out)
{
    int tid = threadIdx.x;
    float l = 0.f;
    if (tid < BATCH) {
        int b = tid;
        float z00 = num_z[(0 * 2 + 0) * BATCH + b];
        float z01 = num_z[(0 * 2 + 1) * BATCH + b];
        float z10 = num_z[(1 * 2 + 0) * BATCH + b];
        float z11 = num_z[(1 * 2 + 1) * BATCH + b];
        float perm0 = z00 + z11;
        float perm1 = z01 + z10;
        float n0, n1;
        if (perm0 >= perm1) { n0 = z00; n1 = z11; }
        else                { n0 = z01; n1 = z10; }
        l = -(n0 - den_z[0 * BATCH + b]) - (n1 - den_z[1 * BATCH + b]);
    }
    #pragma unroll
    for (int o = 32; o > 0; o >>= 1) l += __shfl_down(l, o, 64);
    if (tid == 0) out[0] = l;
}

// ---------------------------------------------------------------------------
extern "C" void kernel_launch(void* const* d_in, const int* in_sizes, int n_in,
                              void* d_out, int out_size, void* d_ws, size_t ws_size,
                              hipStream_t stream) {
    const float* est        = (const float*)d_in[0];
    const int*   seqlen     = (const int*)d_in[1];
    const int*   num_src    = (const int*)d_in[2];
    const int*   num_dst    = (const int*)d_in[3];
    const int*   num_label  = (const int*)d_in[4];
    const float* num_weight = (const float*)d_in[5];
    const float* num_start  = (const float*)d_in[6];
    const float* num_final  = (const float*)d_in[7];
    const int*   den_src    = (const int*)d_in[8];
    const int*   den_dst    = (const int*)d_in[9];
    const int*   den_label  = (const int*)d_in[10];
    const float* den_weight = (const float*)d_in[11];
    const float* den_start  = (const float*)d_in[12];
    const float* den_final  = (const float*)d_in[13];

    char* ws = (char*)d_ws;
    int2*     den_arcs = (int2*)(ws + WS_DEN_ARCS);
    int2*     num_arcs = (int2*)(ws + WS_NUM_ARCS);
    int*      den_cnt  = (int*)(ws + WS_DEN_CNT);
    int*      den_R    = (int*)(ws + WS_DEN_R);
    int*      den_cur  = (int*)(ws + WS_DEN_CUR);
    int*      num_cnt  = (int*)(ws + WS_NUM_CNT);
    int*      num_R    = (int*)(ws + WS_NUM_R);
    int*      num_cur  = (int*)(ws + WS_NUM_CUR);
    float*    galpha   = (float*)(ws + WS_GALPHA);
    float*    gmax     = (float*)(ws + WS_GMAX);
    unsigned* cnt      = (unsigned*)(ws + WS_CNT);
    int*      perm     = (int*)(ws + WS_PERM);
    float*    den_z    = (float*)(ws + WS_DEN_Z);
    float*    num_z    = (float*)(ws + WS_NUM_Z);

    zero_ws<<<512, 256, 0, stream>>>((int*)ws, WS_ZERO_INTS);
    hist_den<<<(DEN_ARCS + 255) / 256, 256, 0, stream>>>(den_dst, den_cnt);
    hist_num<<<(NGRAPH * NUM_ARCS + 255) / 256, 256, 0, stream>>>(num_dst, num_cnt);
    scan_den<<<1, 1024, 0, stream>>>(den_cnt, den_R);
    scan_num<<<NGRAPH, 512, 0, stream>>>(num_cnt, num_R);
    sort_states<<<KCH, 512, 0, stream>>>(den_cnt, perm);
    scat_den<<<(DEN_ARCS + 255) / 256, 256, 0, stream>>>(
        den_src, den_dst, den_label, den_weight, den_R, den_cur, den_arcs);
    scat_num<<<(NGRAPH * NUM_ARCS + 255) / 256, 256, 0, stream>>>(
        num_src, num_dst, num_label, num_weight, num_R, num_cur, num_arcs);

    forward_kernel<<<KCH * NSEQ + S_SPK * S_SPK * BATCH, 1024, 0, stream>>>(
        est, seqlen, den_arcs, den_R, den_start, den_final,
        num_arcs, num_R, num_start, num_final,
        perm, galpha, gmax, cnt, den_z, num_z);

    loss_kernel<<<1, 64, 0, stream>>>(den_z, num_z, (float*)d_out);
}